// Round 5
// baseline (4126.600 us; speedup 1.0000x reference)
//
#include <hip/hip_runtime.h>
#include <hip/hip_bf16.h>

// HeteroNet on MI355X — round 5.
// R4: readout 640us latency/barrier-bound (8% issue util), convs ~270us each
// (serial per-node edge chain). Fixes:
//  (a) readout: A-frags built direct from global (no LDS staging), m in regs,
//      shuffle-butterfly segment flush, LDS 43->9KB, 2 barriers, lb(256,4).
//  (b) conv: edge-parallel with LDS ds_add_f32 accumulation (no dependent
//      chains), then the proven MFMA update phase.

#define NLn 50000
#define NPn 150000
#define En  500000

typedef __attribute__((ext_vector_type(8))) short short8;
typedef __attribute__((ext_vector_type(4))) float float4v;

__device__ __forceinline__ float bf2f(unsigned short u){ return __uint_as_float(((unsigned)u) << 16); }
__device__ __forceinline__ float bflo(unsigned u){ return __uint_as_float(u << 16); }
__device__ __forceinline__ float bfhi(unsigned u){ return __uint_as_float(u & 0xffff0000u); }
__device__ __forceinline__ unsigned short f2bf(float f){
  __hip_bfloat16 h = __float2bfloat16(f);
  return *reinterpret_cast<unsigned short*>(&h);
}
// order-preserving float->uint; enc(v)>0 for all finite v, so 0 == "empty segment"
__device__ __forceinline__ unsigned encf(float f){
  unsigned u = __float_as_uint(f);
  return (u & 0x80000000u) ? ~u : (u | 0x80000000u);
}
__device__ __forceinline__ float tanh_fast(float x){
  return 1.f - 2.f/(__expf(2.f*x) + 1.f);
}

__global__ __launch_bounds__(256) void k_zero(unsigned* __restrict__ p, long n){
  long i = (long)blockIdx.x*256 + threadIdx.x;
  long stride = (long)gridDim.x*256;
  for (; i < n; i += stride) p[i] = 0u;
}

// out[n,c] = sum_k X[n,k]*W[k,c]  ([N,44]@[44,128]) -> bf16
__global__ __launch_bounds__(256) void k_embed(const float* __restrict__ X,
    const float* __restrict__ Wn, unsigned short* __restrict__ out){
  int gid = blockIdx.x*256 + threadIdx.x;
  int n = gid >> 7, c = gid & 127;
  const float* xr = X + (size_t)n*44;
  float acc = 0.f;
  #pragma unroll
  for (int k=0;k<44;k++) acc += xr[k]*Wn[k*128+c];
  out[(size_t)n*128 + c] = f2bf(acc);
}

// v[j] = sum_r W_el[r] * W1[(256+r)*512 + j]
__global__ void k_vvec(const float* __restrict__ Wel, const float* __restrict__ W1,
                       float* __restrict__ v){
  int j = blockIdx.x*256 + threadIdx.x;
  if (j >= 512) return;
  float s = 0.f;
  #pragma unroll
  for (int r=0;r<8;r++) s += Wel[r]*W1[(256+r)*512 + j];
  v[j] = s;
}

// w2t[n][k] = bf16(W2[k][n])   (512x128 -> 128x512)
__global__ __launch_bounds__(256) void k_w2t(const float* __restrict__ W2,
    unsigned short* __restrict__ w2t){
  int gid = blockIdx.x*256 + threadIdx.x;   // 65536
  int n = gid >> 9, k = gid & 511;
  w2t[n*512 + k] = f2bf(W2[k*128 + n]);
}
// wmt[n][k] = bf16(Wm[k][n])   (128x128)
__global__ __launch_bounds__(256) void k_wmt(const float* __restrict__ Wm,
    unsigned short* __restrict__ wmt){
  int gid = blockIdx.x*256 + threadIdx.x;   // 16384
  int n = gid >> 7, k = gid & 127;
  wmt[n*128 + k] = f2bf(Wm[k*128 + n]);
}
// wcat[i][n][k] = bf16( k<128 ? Ws[i][k][n] : Wn[i][k-128][n] )   (6x128x256)
__global__ __launch_bounds__(256) void k_wcat(const float* __restrict__ Ws,
    const float* __restrict__ Wn, unsigned short* __restrict__ wcat){
  int gid = blockIdx.x*256 + threadIdx.x;   // 196608
  int i = gid >> 15, rem = gid & 32767;
  int n = rem >> 8, k = rem & 255;
  float v = (k < 128) ? Ws[i*16384 + k*128 + n] : Wn[i*16384 + (k-128)*128 + n];
  wcat[gid] = f2bf(v);
}
// w1t[part][n][k] = bf16(W1[part*128+k][n])
__global__ __launch_bounds__(256) void k_w1t(const float* __restrict__ W1,
    unsigned short* __restrict__ w1t){
  int gid = blockIdx.x*256 + threadIdx.x;   // 131072 = 2*512*128
  int part = gid >> 16, rem = gid & 65535;
  int n = rem >> 7, k = rem & 127;
  w1t[gid] = f2bf(W1[(part*128 + k)*512 + n]);
}

// ---- CSR construction ----
__global__ __launch_bounds__(256) void k_count(const int* __restrict__ esrc,
    const int* __restrict__ edst, unsigned* __restrict__ cntL, unsigned* __restrict__ cntP){
  int e = blockIdx.x*256 + threadIdx.x;
  if (e >= En) return;
  atomicAdd(&cntL[esrc[e]], 1u);
  atomicAdd(&cntP[edst[e]], 1u);
}
__global__ __launch_bounds__(256) void k_chunkscan(const unsigned* __restrict__ cnt,
    unsigned* __restrict__ rowptr, unsigned* __restrict__ bsum, int n){
  __shared__ unsigned ts[256];
  int tid = threadIdx.x;
  int base = blockIdx.x*1024 + tid*4;
  unsigned v[4], run = 0;
  #pragma unroll
  for (int j=0;j<4;j++){ v[j] = run; run += (base+j < n) ? cnt[base+j] : 0u; }
  ts[tid] = run; __syncthreads();
  for (int off=1; off<256; off<<=1){
    unsigned t = (tid>=off) ? ts[tid-off] : 0u; __syncthreads();
    ts[tid] += t; __syncthreads();
  }
  unsigned excl = ts[tid] - run;
  #pragma unroll
  for (int j=0;j<4;j++) if (base+j < n) rowptr[base+j] = excl + v[j];
  if (tid == 255) bsum[blockIdx.x] = ts[255];
}
__global__ void k_scanb(unsigned* __restrict__ bsum, int nc){
  __shared__ unsigned ts[256];
  int tid = threadIdx.x;
  unsigned x = (tid < nc) ? bsum[tid] : 0u;
  ts[tid] = x; __syncthreads();
  for (int off=1; off<256; off<<=1){
    unsigned t = (tid>=off) ? ts[tid-off] : 0u; __syncthreads();
    ts[tid] += t; __syncthreads();
  }
  if (tid < nc) bsum[tid] = ts[tid] - x;
}
__global__ __launch_bounds__(256) void k_addoff(unsigned* __restrict__ rowptr,
    unsigned* __restrict__ cursor, const unsigned* __restrict__ bsum, int n){
  int i = blockIdx.x*256 + threadIdx.x;
  if (i < n){
    unsigned r = rowptr[i] + bsum[i>>10];
    rowptr[i] = r; cursor[i] = r;
  }
  if (i == 0) rowptr[n] = En;
}
__global__ __launch_bounds__(256) void k_place(const int* __restrict__ esrc,
    const int* __restrict__ edst, const float* __restrict__ ea,
    const int* __restrict__ lbatch, unsigned* __restrict__ curL,
    unsigned* __restrict__ curP, uint4* __restrict__ edgeL,
    uint4* __restrict__ rbfL, int* __restrict__ srcP, uint4* __restrict__ rbfP){
  int e = blockIdx.x*256 + threadIdx.x;
  if (e >= En) return;
  int s = esrc[e], d = edst[e];
  float dd = ea[e];
  unsigned short r[8];
  #pragma unroll
  for (int j=0;j<8;j++){
    float a = (dd - 0.7142857143f*(float)j) * 1.6f;   // mu=linspace(0,5,8), sigma=5/8
    r[j] = f2bf(__expf(-a*a));
  }
  uint4 rp;
  rp.x = (unsigned)r[0] | ((unsigned)r[1]<<16);
  rp.y = (unsigned)r[2] | ((unsigned)r[3]<<16);
  rp.z = (unsigned)r[4] | ((unsigned)r[5]<<16);
  rp.w = (unsigned)r[6] | ((unsigned)r[7]<<16);
  unsigned pl = atomicAdd(&curL[s], 1u);
  uint4 er; er.x = (unsigned)s; er.y = (unsigned)d;
  er.z = __float_as_uint(dd); er.w = (unsigned)lbatch[s];
  edgeL[pl] = er; rbfL[pl] = rp;
  unsigned pp = atomicAdd(&curP[d], 1u);
  srcP[pp] = s; rbfP[pp] = rp;
}

// ---- edge-parallel fused conv: LDS-atomic aggregate + MFMA update ----
// 32 dst nodes/block. agg[n] = mean_e silu(rbf_e@Wb+bb)*x_src[e];
// out = lrelu([x_dst|agg]@wcat + bias); xout = out; xsum += out.
#define CV_WIN 512
__global__ __launch_bounds__(256) void k_conv(
    const unsigned short* __restrict__ xdst_in, const unsigned short* __restrict__ xsrc_in,
    const unsigned* __restrict__ rowptr, const int* __restrict__ eidx, int estride,
    const uint4* __restrict__ rbfpk,
    const float* __restrict__ Wb_i, const float* __restrict__ bb_i,
    const unsigned short* __restrict__ wcat, const float* __restrict__ bias,
    unsigned short* __restrict__ xout, unsigned short* __restrict__ xsum, int ndst){
  // region0 (17664B): aggL[32][128] f32 + rps[33] u32 + erow[512] u16; ob aliases it
  // region1 (16896B): ab[32][264] bf16
  __shared__ __align__(16) char smem[34560];
  float (*aggL)[128]          = (float(*)[128])smem;
  unsigned* rps               = (unsigned*)(smem + 16384);
  unsigned short* erow        = (unsigned short*)(smem + 16520);
  float (*ob)[132]            = (float(*)[132])smem;               // aliases aggL+
  unsigned short (*ab)[264]   = (unsigned short(*)[264])(smem + 17664);

  int tid = threadIdx.x, c = tid & 127, sub = tid >> 7;
  int n0 = blockIdx.x*32;
  if (tid < 33){
    int idx = n0 + tid; if (idx > ndst) idx = ndst;
    rps[tid] = rowptr[idx];
  }
  {
    float* fl = (float*)aggL;
    #pragma unroll
    for (int j=0;j<16;j++) fl[tid + j*256] = 0.f;
  }
  float wb[8];
  #pragma unroll
  for (int j=0;j<8;j++) wb[j] = Wb_i[j*128 + c];
  float bbc = bb_i[c];
  __syncthreads();

  int r00 = (int)rps[0], rEnd = (int)rps[32];
  for (int base = r00; base < rEnd; base += CV_WIN){
    int wend = base + CV_WIN; if (wend > rEnd) wend = rEnd;
    if (tid < 32){
      int a = (int)rps[tid], b = (int)rps[tid+1];
      if (a < base) a = base;
      if (b > wend) b = wend;
      for (int p = a; p < b; p++) erow[p - base] = (unsigned short)tid;
    }
    __syncthreads();
    for (int p = base + sub; p < wend; p += 2){
      int row = erow[p - base];
      uint4 rp = rbfpk[p];                            // uniform -> broadcast
      int sn = eidx[(size_t)p*estride];               // uniform -> broadcast
      const unsigned short* rs = (const unsigned short*)&rp;
      float s = bbc;
      #pragma unroll
      for (int j=0;j<8;j++) s += bf2f(rs[j])*wb[j];
      float basec = s / (1.f + __expf(-s));           // silu
      float x = bf2f(xsrc_in[(size_t)sn*128 + c]);
      atomicAdd(&aggL[row][c], basec*x);              // ds_add_f32, no return dep
    }
    __syncthreads();
  }

  // build A = [x_dst | agg*1/deg] (bf16)
  int hh = sub;
  for (int m = hh*16; m < hh*16+16; m++){
    int n = n0 + m;
    if (n < ndst){
      ab[m][c] = xdst_in[(size_t)n*128 + c];
      int dg = (int)(rps[m+1] - rps[m]);
      float inv = 1.f / (float)(dg > 1 ? dg : 1);
      ab[m][128 + c] = f2bf(aggL[m][c] * inv);
    } else { ab[m][c] = 0; ab[m][128 + c] = 0; }
  }
  __syncthreads();   // aggL dead; ob may now alias it

  int wave = tid >> 6, lane = tid & 63, quad = lane >> 4, l15 = lane & 15;
  int mt = wave & 1, nh = wave >> 1;
  int arow = mt*16 + l15;
  float4v acc[4] = {{0,0,0,0},{0,0,0,0},{0,0,0,0},{0,0,0,0}};
  for (int k0 = 0; k0 < 256; k0 += 32){
    short8 A = *(const short8*)&ab[arow][k0 + quad*8];
    #pragma unroll
    for (int nt=0;nt<4;nt++){
      short8 B = *(const short8*)&wcat[(size_t)(nh*64 + nt*16 + l15)*256 + k0 + quad*8];
      acc[nt] = __builtin_amdgcn_mfma_f32_16x16x32_bf16(A, B, acc[nt], 0, 0, 0);
    }
  }
  #pragma unroll
  for (int nt=0;nt<4;nt++){
    int col = nh*64 + nt*16 + l15;
    float bc = bias[col];
    #pragma unroll
    for (int r=0;r<4;r++){
      int row = mt*16 + quad*4 + r;
      float v = acc[nt][r] + bc;
      ob[row][col] = (v > 0.f) ? v : 0.01f*v;         // leaky_relu
    }
  }
  __syncthreads();
  for (int m = hh*16; m < hh*16+16; m++){
    int n = n0 + m;
    if (n < ndst){
      float v = ob[m][c];
      size_t off = (size_t)n*128 + c;
      xout[off] = f2bf(v);
      xsum[off] = f2bf(bf2f(xsum[off]) + v);
    }
  }
}

// ---- MFMA hproj: h[n][512] = xsum[n][128] @ w1t^T (+ optional bias), 32 nodes/blk
__global__ __launch_bounds__(256) void k_hproj_mfma(
    const unsigned short* __restrict__ xs, const unsigned short* __restrict__ w1t,
    const float* __restrict__ bias, unsigned* __restrict__ hout, int nn){
  __shared__ unsigned short hb[32][528];
  int tid = threadIdx.x;
  int wave = tid >> 6, lane = tid & 63, quad = lane >> 4, l15 = lane & 15;
  int mt = wave & 1, nh = wave >> 1;
  int n0 = blockIdx.x*32;
  int an = n0 + mt*16 + l15; if (an >= nn) an = nn - 1;
  const unsigned short* aptr = xs + (size_t)an*128;
  float4v acc[16];
  #pragma unroll
  for (int i=0;i<16;i++) acc[i] = (float4v){0,0,0,0};
  for (int k0 = 0; k0 < 128; k0 += 32){
    short8 A = *(const short8*)&aptr[k0 + quad*8];
    #pragma unroll
    for (int nt=0;nt<16;nt++){
      short8 B = *(const short8*)&w1t[(size_t)(nh*256 + nt*16 + l15)*128 + k0 + quad*8];
      acc[nt] = __builtin_amdgcn_mfma_f32_16x16x32_bf16(A, B, acc[nt], 0, 0, 0);
    }
  }
  #pragma unroll
  for (int nt=0;nt<16;nt++){
    int col = nh*256 + nt*16 + l15;
    float bv = bias ? bias[col] : 0.f;
    #pragma unroll
    for (int r=0;r<4;r++) hb[mt*16 + quad*4 + r][col] = f2bf(acc[nt][r] + bv);
  }
  __syncthreads();
  for (int m=0;m<32;m++){
    int n = n0 + m;
    if (n < nn){
      unsigned pack = (unsigned)hb[m][2*tid] | ((unsigned)hb[m][2*tid+1] << 16);
      hout[(size_t)n*256 + tid] = pack;
    }
  }
}

// ---- readout: 32 edges/block, A-frags direct from global, m in registers,
//      shuffle-butterfly segment flush. b1 pre-folded into h_l.
__global__ __launch_bounds__(256, 4) void k_readout2(
    const unsigned* __restrict__ hl, const unsigned* __restrict__ hp,
    const uint4* __restrict__ edgeL, const float* __restrict__ vvec,
    const unsigned short* __restrict__ w2t, const float* __restrict__ b2,
    const unsigned short* __restrict__ wmt, const float* __restrict__ bm,
    float* __restrict__ outw, unsigned* __restrict__ mmax){
  __shared__ unsigned short msb[32][136];
  __shared__ int sidx[32], didx[32], bsh[32];
  __shared__ float dsts[32];
  int tid = threadIdx.x;
  int e0 = blockIdx.x*32;
  if (tid < 32){
    uint4 er = edgeL[e0 + tid];
    sidx[tid] = (int)er.x; didx[tid] = (int)er.y;
    dsts[tid] = __uint_as_float(er.z); bsh[tid] = (int)er.w;
  }
  __syncthreads();
  int wave = tid >> 6, lane = tid & 63, quad = lane >> 4, l15 = lane & 15;
  int mt = wave & 1, ns = (wave >> 1)*64;
  int arow = mt*16 + l15;
  const unsigned* hlr = hl + (size_t)sidx[arow]*256;
  const unsigned* hpr = hp + (size_t)didx[arow]*256;
  float dd = dsts[arow];

  // GEMM1: m[32,128] = relu(h)[32,512] @ W2^T; A built on the fly
  float4v acc[4] = {{0,0,0,0},{0,0,0,0},{0,0,0,0},{0,0,0,0}};
  for (int k0 = 0; k0 < 512; k0 += 32){
    int dw = (k0 >> 1) + quad*4;
    uint4 ua = *(const uint4*)&hlr[dw];
    uint4 ub = *(const uint4*)&hpr[dw];
    float4 v0 = *(const float4*)&vvec[2*dw];
    float4 v1 = *(const float4*)&vvec[2*dw + 4];
    const unsigned* uap = (const unsigned*)&ua;
    const unsigned* ubp = (const unsigned*)&ub;
    const float* vp = (const float*)&v0;   // v0,v1 contiguous? not guaranteed — handle split
    union { unsigned u[4]; short8 s; } A;
    #pragma unroll
    for (int i=0;i<4;i++){
      float vlo = (i<2) ? ((i==0)? v0.x : v0.z) : ((i==2)? v1.x : v1.z);
      float vhi = (i<2) ? ((i==0)? v0.y : v0.w) : ((i==2)? v1.y : v1.w);
      float lo = fmaxf(bflo(uap[i]) + bflo(ubp[i]) + dd*vlo, 0.f);
      float hi = fmaxf(bfhi(uap[i]) + bfhi(ubp[i]) + dd*vhi, 0.f);
      A.u[i] = (unsigned)f2bf(lo) | ((unsigned)f2bf(hi) << 16);
    }
    (void)vp;
    #pragma unroll
    for (int nt=0;nt<4;nt++){
      short8 B = *(const short8*)&w2t[(size_t)(ns + nt*16 + l15)*512 + k0 + quad*8];
      acc[nt] = __builtin_amdgcn_mfma_f32_16x16x32_bf16(A.s, B, acc[nt], 0, 0, 0);
    }
  }
  float mreg[4][4];
  #pragma unroll
  for (int nt=0;nt<4;nt++){
    int col = ns + nt*16 + l15;
    float b2c = b2[col];
    #pragma unroll
    for (int r=0;r<4;r++){
      int row = mt*16 + quad*4 + r;
      float mv = acc[nt][r] + b2c;
      mreg[nt][r] = mv;
      msb[row][col] = f2bf(mv);
    }
  }
  __syncthreads();

  // GEMM2: t = tanh(m@Wm + bm); flush sum(t*m), max(m) per batch
  float4v acc2[4] = {{0,0,0,0},{0,0,0,0},{0,0,0,0},{0,0,0,0}};
  for (int k0 = 0; k0 < 128; k0 += 32){
    short8 a = *(const short8*)&msb[arow][k0 + quad*8];
    #pragma unroll
    for (int nt=0;nt<4;nt++){
      short8 B = *(const short8*)&wmt[(size_t)(ns + nt*16 + l15)*128 + k0 + quad*8];
      acc2[nt] = __builtin_amdgcn_mfma_f32_16x16x32_bf16(a, B, acc2[nt], 0, 0, 0);
    }
  }
  bool uni = (bsh[0] == bsh[31]);
  int b0 = bsh[0];
  #pragma unroll
  for (int nt=0;nt<4;nt++){
    int col = ns + nt*16 + l15;
    float bmc = bm[col];
    float wmv[4];
    #pragma unroll
    for (int r=0;r<4;r++){
      float t = tanh_fast(acc2[nt][r] + bmc);
      wmv[r] = t * mreg[nt][r];
    }
    if (uni){
      float s = (wmv[0]+wmv[1]) + (wmv[2]+wmv[3]);
      float mx = fmaxf(fmaxf(mreg[nt][0],mreg[nt][1]), fmaxf(mreg[nt][2],mreg[nt][3]));
      s += __shfl_xor(s, 16); s += __shfl_xor(s, 32);
      mx = fmaxf(mx, __shfl_xor(mx, 16)); mx = fmaxf(mx, __shfl_xor(mx, 32));
      if (quad == 0){
        atomicAdd(&outw[b0*256 + col], s);
        atomicMax(&mmax[b0*128 + col], encf(mx));
      }
    } else {
      #pragma unroll
      for (int r=0;r<4;r++){
        int b = bsh[mt*16 + quad*4 + r];
        atomicAdd(&outw[b*256 + col], wmv[r]);
        atomicMax(&mmax[b*128 + col], encf(mreg[nt][r]));
      }
    }
  }
}

__global__ __launch_bounds__(256) void k_final(const unsigned* __restrict__ mmax,
    float* __restrict__ out){
  int gid = blockIdx.x*256 + threadIdx.x;   // 32768 = 256*128
  unsigned enc = mmax[gid];
  float v;
  if (enc == 0u) v = 0.f;
  else if (enc & 0x80000000u) v = __uint_as_float(enc & 0x7FFFFFFFu);
  else v = __uint_as_float(~enc);
  int g = gid >> 7, cc = gid & 127;
  out[g*256 + 128 + cc] = v;
}

extern "C" void kernel_launch(void* const* d_in, const int* in_sizes, int n_in,
                              void* d_out, int out_size, void* d_ws, size_t ws_size,
                              hipStream_t stream) {
  const float* x_l    = (const float*)d_in[0];
  const float* x_p    = (const float*)d_in[1];
  const float* ea     = (const float*)d_in[2];
  const int*   esrc   = (const int*)d_in[3];
  const int*   edst   = (const int*)d_in[4];
  const int*   lbatch = (const int*)d_in[5];
  const float* W_node = (const float*)d_in[6];
  const float* W_el   = (const float*)d_in[7];
  const float* Wb     = (const float*)d_in[8];
  const float* bb     = (const float*)d_in[9];
  const float* Wn     = (const float*)d_in[10];
  const float* Ws     = (const float*)d_in[11];
  const float* bconv  = (const float*)d_in[12];
  const float* W1     = (const float*)d_in[13];
  const float* b1     = (const float*)d_in[14];
  const float* W2     = (const float*)d_in[15];
  const float* b2     = (const float*)d_in[16];
  const float* Wm     = (const float*)d_in[17];
  const float* bm     = (const float*)d_in[18];

  // ---- workspace layout (decimal offsets), peak < 256 MiB ----
  char* w = (char*)d_ws;
  unsigned short* xl0 = (unsigned short*)(w + 0);
  unsigned short* xl1 = (unsigned short*)(w + 12800000);
  unsigned short* xp0 = (unsigned short*)(w + 25600000);
  unsigned short* xp1 = (unsigned short*)(w + 64000000);
  int*      srcP  = (int*)(w + 102400000);
  uint4*    rbfP  = (uint4*)(w + 104400000);
  uint4*    rbfL  = (uint4*)(w + 112400000);
  unsigned* h_l   = (unsigned*)(w + 0);
  unsigned* h_p   = (unsigned*)(w + 51200000);
  unsigned short* xl_s = (unsigned short*)(w + 204800000);
  unsigned short* xp_s = (unsigned short*)(w + 217600000);
  unsigned short* wcat = (unsigned short*)(w + 256000000);
  unsigned short* w1t  = (unsigned short*)(w + 256393216);
  unsigned short* w2t  = (unsigned short*)(w + 256655360);
  unsigned short* wmt  = (unsigned short*)(w + 256786432);
  float*    vvec  = (float*)(w + 256819200);
  unsigned* mmax  = (unsigned*)(w + 256821248);
  unsigned* bsumL = (unsigned*)(w + 256952320);
  unsigned* bsumP = (unsigned*)(w + 256953344);
  unsigned* rowptrL = (unsigned*)(w + 256954368);
  unsigned* cursorL = (unsigned*)(w + 257154432);
  unsigned* rowptrP = (unsigned*)(w + 257354432);
  unsigned* cursorP = (unsigned*)(w + 257954496);
  unsigned* cntL    = (unsigned*)(w + 258554496);
  unsigned* cntP    = (unsigned*)(w + 258754496);
  uint4*    edgeL   = (uint4*)(w + 259354496);   // {src, dst, bits(d), batch}

  float* out = (float*)d_out;

  k_zero<<<1024, 256, 0, stream>>>((unsigned*)(w + 204800000), 51200000/4);  // xl_s+xp_s
  k_zero<<<196, 256, 0, stream>>>((unsigned*)(w + 258554496), 800000/4);     // cntL+cntP
  k_zero<<<128, 256, 0, stream>>>(mmax, 131072/4);
  k_zero<<<256, 256, 0, stream>>>((unsigned*)d_out, 262144/4);

  k_embed<<<25000, 256, 0, stream>>>(x_l, W_node, xl0);
  k_embed<<<75000, 256, 0, stream>>>(x_p, W_node, xp0);
  k_vvec<<<2, 256, 0, stream>>>(W_el, W1, vvec);
  k_w2t<<<256, 256, 0, stream>>>(W2, w2t);
  k_wmt<<<64, 256, 0, stream>>>(Wm, wmt);
  k_wcat<<<768, 256, 0, stream>>>(Ws, Wn, wcat);
  k_w1t<<<512, 256, 0, stream>>>(W1, w1t);

  k_count<<<1954, 256, 0, stream>>>(esrc, edst, cntL, cntP);
  k_chunkscan<<<49, 256, 0, stream>>>(cntL, rowptrL, bsumL, NLn);
  k_chunkscan<<<147, 256, 0, stream>>>(cntP, rowptrP, bsumP, NPn);
  k_scanb<<<1, 256, 0, stream>>>(bsumL, 49);
  k_scanb<<<1, 256, 0, stream>>>(bsumP, 147);
  k_addoff<<<196, 256, 0, stream>>>(rowptrL, cursorL, bsumL, NLn);
  k_addoff<<<586, 256, 0, stream>>>(rowptrP, cursorP, bsumP, NPn);
  k_place<<<1954, 256, 0, stream>>>(esrc, edst, ea, lbatch, cursorL, cursorP,
                                    edgeL, rbfL, srcP, rbfP);

  unsigned short *xlc = xl0, *xln = xl1, *xpc = xp0, *xpn = xp1;
  for (int l = 0; l < 3; ++l){
    int ilp = 2*l, ipl = 2*l + 1;
    k_conv<<<4688, 256, 0, stream>>>(xpc, xlc, rowptrP, srcP, 1, rbfP,
        Wb + ilp*1024, bb + ilp*128, wcat + ilp*32768, bconv + ilp*128,
        xpn, xp_s, NPn);
    k_conv<<<1563, 256, 0, stream>>>(xlc, xpc, rowptrL, (const int*)edgeL + 1, 4, rbfL,
        Wb + ipl*1024, bb + ipl*128, wcat + ipl*32768, bconv + ipl*128,
        xln, xl_s, NLn);
    unsigned short* t;
    t = xlc; xlc = xln; xln = t;
    t = xpc; xpc = xpn; xpn = t;
  }

  // b1 folded into h_l here (bias arg); protein part gets no bias
  k_hproj_mfma<<<1563, 256, 0, stream>>>(xl_s, w1t, b1, h_l, NLn);
  k_hproj_mfma<<<4688, 256, 0, stream>>>(xp_s, w1t + 65536, nullptr, h_p, NPn);

  k_readout2<<<En/32, 256, 0, stream>>>(h_l, h_p, edgeL, vvec,
                                        w2t, b2, wmt, bm, out, mmax);
  k_final<<<128, 256, 0, stream>>>(mmax, out);
}

// Round 6
// 2226.202 us; speedup vs baseline: 1.8536x; 1.8536x over previous
//
#include <hip/hip_runtime.h>
#include <hip/hip_bf16.h>

// HeteroNet on MI355X — round 6.
// R5 post-mortem: edge-parallel conv regressed ~1100us (erow/LDS-atomic machinery);
// readout at 90% occupancy got WORSE (gathers moved into dependent MFMA loop, 2x
// redundant fetch). R6: conv = R4 structure + unroll-2 MLP; readout = R4 coalesced
// LDS staging + (M32,N32) wave tiles (B-operand L2 traffic 4GB->2GB, no intra-block
// redundancy) + m in registers + shuffle flush (LDS 43->34KB, 4 blocks/CU).

#define NLn 50000
#define NPn 150000
#define En  500000

typedef __attribute__((ext_vector_type(8))) short short8;
typedef __attribute__((ext_vector_type(4))) float float4v;

__device__ __forceinline__ float bf2f(unsigned short u){ return __uint_as_float(((unsigned)u) << 16); }
__device__ __forceinline__ float bflo(unsigned u){ return __uint_as_float(u << 16); }
__device__ __forceinline__ float bfhi(unsigned u){ return __uint_as_float(u & 0xffff0000u); }
__device__ __forceinline__ unsigned short f2bf(float f){
  __hip_bfloat16 h = __float2bfloat16(f);
  return *reinterpret_cast<unsigned short*>(&h);
}
// order-preserving float->uint; enc(v)>0 for all finite v, so 0 == "empty segment"
__device__ __forceinline__ unsigned encf(float f){
  unsigned u = __float_as_uint(f);
  return (u & 0x80000000u) ? ~u : (u | 0x80000000u);
}
__device__ __forceinline__ float tanh_fast(float x){
  return 1.f - 2.f/(__expf(2.f*x) + 1.f);
}

__global__ __launch_bounds__(256) void k_zero(unsigned* __restrict__ p, long n){
  long i = (long)blockIdx.x*256 + threadIdx.x;
  long stride = (long)gridDim.x*256;
  for (; i < n; i += stride) p[i] = 0u;
}

// out[n,c] = sum_k X[n,k]*W[k,c]  ([N,44]@[44,128]) -> bf16
__global__ __launch_bounds__(256) void k_embed(const float* __restrict__ X,
    const float* __restrict__ Wn, unsigned short* __restrict__ out){
  int gid = blockIdx.x*256 + threadIdx.x;
  int n = gid >> 7, c = gid & 127;
  const float* xr = X + (size_t)n*44;
  float acc = 0.f;
  #pragma unroll
  for (int k=0;k<44;k++) acc += xr[k]*Wn[k*128+c];
  out[(size_t)n*128 + c] = f2bf(acc);
}

// v[j] = sum_r W_el[r] * W1[(256+r)*512 + j]
__global__ void k_vvec(const float* __restrict__ Wel, const float* __restrict__ W1,
                       float* __restrict__ v){
  int j = blockIdx.x*256 + threadIdx.x;
  if (j >= 512) return;
  float s = 0.f;
  #pragma unroll
  for (int r=0;r<8;r++) s += Wel[r]*W1[(256+r)*512 + j];
  v[j] = s;
}

// w2t[n][k] = bf16(W2[k][n])   (512x128 -> 128x512)
__global__ __launch_bounds__(256) void k_w2t(const float* __restrict__ W2,
    unsigned short* __restrict__ w2t){
  int gid = blockIdx.x*256 + threadIdx.x;   // 65536
  int n = gid >> 9, k = gid & 511;
  w2t[n*512 + k] = f2bf(W2[k*128 + n]);
}
// wmt[n][k] = bf16(Wm[k][n])   (128x128)
__global__ __launch_bounds__(256) void k_wmt(const float* __restrict__ Wm,
    unsigned short* __restrict__ wmt){
  int gid = blockIdx.x*256 + threadIdx.x;   // 16384
  int n = gid >> 7, k = gid & 127;
  wmt[n*128 + k] = f2bf(Wm[k*128 + n]);
}
// wcat[i][n][k] = bf16( k<128 ? Ws[i][k][n] : Wn[i][k-128][n] )   (6x128x256)
__global__ __launch_bounds__(256) void k_wcat(const float* __restrict__ Ws,
    const float* __restrict__ Wn, unsigned short* __restrict__ wcat){
  int gid = blockIdx.x*256 + threadIdx.x;   // 196608
  int i = gid >> 15, rem = gid & 32767;
  int n = rem >> 8, k = rem & 255;
  float v = (k < 128) ? Ws[i*16384 + k*128 + n] : Wn[i*16384 + (k-128)*128 + n];
  wcat[gid] = f2bf(v);
}
// w1t[part][n][k] = bf16(W1[part*128+k][n])
__global__ __launch_bounds__(256) void k_w1t(const float* __restrict__ W1,
    unsigned short* __restrict__ w1t){
  int gid = blockIdx.x*256 + threadIdx.x;   // 131072 = 2*512*128
  int part = gid >> 16, rem = gid & 65535;
  int n = rem >> 7, k = rem & 127;
  w1t[gid] = f2bf(W1[(part*128 + k)*512 + n]);
}

// ---- CSR construction ----
__global__ __launch_bounds__(256) void k_count(const int* __restrict__ esrc,
    const int* __restrict__ edst, unsigned* __restrict__ cntL, unsigned* __restrict__ cntP){
  int e = blockIdx.x*256 + threadIdx.x;
  if (e >= En) return;
  atomicAdd(&cntL[esrc[e]], 1u);
  atomicAdd(&cntP[edst[e]], 1u);
}
__global__ __launch_bounds__(256) void k_chunkscan(const unsigned* __restrict__ cnt,
    unsigned* __restrict__ rowptr, unsigned* __restrict__ bsum, int n){
  __shared__ unsigned ts[256];
  int tid = threadIdx.x;
  int base = blockIdx.x*1024 + tid*4;
  unsigned v[4], run = 0;
  #pragma unroll
  for (int j=0;j<4;j++){ v[j] = run; run += (base+j < n) ? cnt[base+j] : 0u; }
  ts[tid] = run; __syncthreads();
  for (int off=1; off<256; off<<=1){
    unsigned t = (tid>=off) ? ts[tid-off] : 0u; __syncthreads();
    ts[tid] += t; __syncthreads();
  }
  unsigned excl = ts[tid] - run;
  #pragma unroll
  for (int j=0;j<4;j++) if (base+j < n) rowptr[base+j] = excl + v[j];
  if (tid == 255) bsum[blockIdx.x] = ts[255];
}
__global__ void k_scanb(unsigned* __restrict__ bsum, int nc){
  __shared__ unsigned ts[256];
  int tid = threadIdx.x;
  unsigned x = (tid < nc) ? bsum[tid] : 0u;
  ts[tid] = x; __syncthreads();
  for (int off=1; off<256; off<<=1){
    unsigned t = (tid>=off) ? ts[tid-off] : 0u; __syncthreads();
    ts[tid] += t; __syncthreads();
  }
  if (tid < nc) bsum[tid] = ts[tid] - x;
}
__global__ __launch_bounds__(256) void k_addoff(unsigned* __restrict__ rowptr,
    unsigned* __restrict__ cursor, const unsigned* __restrict__ bsum, int n){
  int i = blockIdx.x*256 + threadIdx.x;
  if (i < n){
    unsigned r = rowptr[i] + bsum[i>>10];
    rowptr[i] = r; cursor[i] = r;
  }
  if (i == 0) rowptr[n] = En;
}
__global__ __launch_bounds__(256) void k_place(const int* __restrict__ esrc,
    const int* __restrict__ edst, const float* __restrict__ ea,
    const int* __restrict__ lbatch, unsigned* __restrict__ curL,
    unsigned* __restrict__ curP, uint4* __restrict__ edgeL,
    uint4* __restrict__ rbfL, int* __restrict__ srcP, uint4* __restrict__ rbfP){
  int e = blockIdx.x*256 + threadIdx.x;
  if (e >= En) return;
  int s = esrc[e], d = edst[e];
  float dd = ea[e];
  unsigned short r[8];
  #pragma unroll
  for (int j=0;j<8;j++){
    float a = (dd - 0.7142857143f*(float)j) * 1.6f;   // mu=linspace(0,5,8), sigma=5/8
    r[j] = f2bf(__expf(-a*a));
  }
  uint4 rp;
  rp.x = (unsigned)r[0] | ((unsigned)r[1]<<16);
  rp.y = (unsigned)r[2] | ((unsigned)r[3]<<16);
  rp.z = (unsigned)r[4] | ((unsigned)r[5]<<16);
  rp.w = (unsigned)r[6] | ((unsigned)r[7]<<16);
  unsigned pl = atomicAdd(&curL[s], 1u);
  uint4 er; er.x = (unsigned)s; er.y = (unsigned)d;
  er.z = __float_as_uint(dd); er.w = (unsigned)lbatch[s];
  edgeL[pl] = er; rbfL[pl] = rp;
  unsigned pp = atomicAdd(&curP[d], 1u);
  srcP[pp] = s; rbfP[pp] = rp;
}

// ---- fused conv (R4 structure + unroll-2 MLP): CSR aggregate + MFMA update ----
// 32 dst nodes/block. agg[n] = mean_e silu(rbf_e@Wb+bb)*x_src[e];
// out = lrelu([x_dst|agg]@wcat + bias); xout = out; xsum += out.
__global__ __launch_bounds__(256) void k_conv(
    const unsigned short* __restrict__ xdst_in, const unsigned short* __restrict__ xsrc_in,
    const unsigned* __restrict__ rowptr, const int* __restrict__ eidx, int estride,
    const uint4* __restrict__ rbfpk,
    const float* __restrict__ Wb_i, const float* __restrict__ bb_i,
    const unsigned short* __restrict__ wcat, const float* __restrict__ bias,
    unsigned short* __restrict__ xout, unsigned short* __restrict__ xsum, int ndst){
  __shared__ unsigned short ab[32][264];   // [m][k]: k<128 x_dst, k>=128 agg (bf16)
  __shared__ float ob[32][132];
  int tid = threadIdx.x, c = tid & 127, hh = tid >> 7;
  int n0 = blockIdx.x*32;
  float wb[8];
  #pragma unroll
  for (int j=0;j<8;j++) wb[j] = Wb_i[j*128 + c];
  float bbc = bb_i[c];
  for (int m = hh*16; m < hh*16+16; m++){
    int n = n0 + m;
    float a0 = 0.f, a1 = 0.f;
    int dg = 1;
    if (n < ndst){
      ab[m][c] = xdst_in[(size_t)n*128 + c];
      int r0 = (int)rowptr[n], r1 = (int)rowptr[n+1];
      dg = r1 - r0;
      int p = r0;
      for (; p + 1 < r1; p += 2){               // two independent gather chains
        uint4 rpA = rbfpk[p];
        uint4 rpB = rbfpk[p+1];
        int snA = eidx[(size_t)p*estride];
        int snB = eidx[(size_t)(p+1)*estride];
        const unsigned short* rsA = (const unsigned short*)&rpA;
        const unsigned short* rsB = (const unsigned short*)&rpB;
        float sA = bbc, sB = bbc;
        #pragma unroll
        for (int j=0;j<8;j++){ sA += bf2f(rsA[j])*wb[j]; sB += bf2f(rsB[j])*wb[j]; }
        float bA = sA / (1.f + __expf(-sA));
        float bB = sB / (1.f + __expf(-sB));
        a0 += bA * bf2f(xsrc_in[(size_t)snA*128 + c]);
        a1 += bB * bf2f(xsrc_in[(size_t)snB*128 + c]);
      }
      if (p < r1){
        uint4 rpA = rbfpk[p];
        int snA = eidx[(size_t)p*estride];
        const unsigned short* rsA = (const unsigned short*)&rpA;
        float sA = bbc;
        #pragma unroll
        for (int j=0;j<8;j++) sA += bf2f(rsA[j])*wb[j];
        a0 += (sA / (1.f + __expf(-sA))) * bf2f(xsrc_in[(size_t)snA*128 + c]);
      }
    } else {
      ab[m][c] = 0;
    }
    float inv = 1.f / (float)(dg > 1 ? dg : 1);
    ab[m][128 + c] = f2bf((a0 + a1) * inv);
  }
  __syncthreads();
  int wave = tid >> 6, lane = tid & 63, quad = lane >> 4, l15 = lane & 15;
  int mt = wave & 1, nh = wave >> 1;
  int arow = mt*16 + l15;
  float4v acc[4] = {{0,0,0,0},{0,0,0,0},{0,0,0,0},{0,0,0,0}};
  for (int k0 = 0; k0 < 256; k0 += 32){
    short8 A = *(const short8*)&ab[arow][k0 + quad*8];
    #pragma unroll
    for (int nt=0;nt<4;nt++){
      short8 B = *(const short8*)&wcat[(size_t)(nh*64 + nt*16 + l15)*256 + k0 + quad*8];
      acc[nt] = __builtin_amdgcn_mfma_f32_16x16x32_bf16(A, B, acc[nt], 0, 0, 0);
    }
  }
  #pragma unroll
  for (int nt=0;nt<4;nt++){
    int col = nh*64 + nt*16 + l15;
    float bc = bias[col];
    #pragma unroll
    for (int r=0;r<4;r++){
      int row = mt*16 + quad*4 + r;
      float v = acc[nt][r] + bc;
      ob[row][col] = (v > 0.f) ? v : 0.01f*v;         // leaky_relu
    }
  }
  __syncthreads();
  for (int m = hh*16; m < hh*16+16; m++){
    int n = n0 + m;
    if (n < ndst){
      float v = ob[m][c];
      size_t off = (size_t)n*128 + c;
      xout[off] = f2bf(v);
      xsum[off] = f2bf(bf2f(xsum[off]) + v);
    }
  }
}

// ---- MFMA hproj: h[n][512] = xsum[n][128] @ w1t^T (+ optional bias), 32 nodes/blk
__global__ __launch_bounds__(256) void k_hproj_mfma(
    const unsigned short* __restrict__ xs, const unsigned short* __restrict__ w1t,
    const float* __restrict__ bias, unsigned* __restrict__ hout, int nn){
  __shared__ unsigned short hb[32][528];
  int tid = threadIdx.x;
  int wave = tid >> 6, lane = tid & 63, quad = lane >> 4, l15 = lane & 15;
  int mt = wave & 1, nh = wave >> 1;
  int n0 = blockIdx.x*32;
  int an = n0 + mt*16 + l15; if (an >= nn) an = nn - 1;
  const unsigned short* aptr = xs + (size_t)an*128;
  float4v acc[16];
  #pragma unroll
  for (int i=0;i<16;i++) acc[i] = (float4v){0,0,0,0};
  for (int k0 = 0; k0 < 128; k0 += 32){
    short8 A = *(const short8*)&aptr[k0 + quad*8];
    #pragma unroll
    for (int nt=0;nt<16;nt++){
      short8 B = *(const short8*)&w1t[(size_t)(nh*256 + nt*16 + l15)*128 + k0 + quad*8];
      acc[nt] = __builtin_amdgcn_mfma_f32_16x16x32_bf16(A, B, acc[nt], 0, 0, 0);
    }
  }
  #pragma unroll
  for (int nt=0;nt<16;nt++){
    int col = nh*256 + nt*16 + l15;
    float bv = bias ? bias[col] : 0.f;
    #pragma unroll
    for (int r=0;r<4;r++) hb[mt*16 + quad*4 + r][col] = f2bf(acc[nt][r] + bv);
  }
  __syncthreads();
  for (int m=0;m<32;m++){
    int n = n0 + m;
    if (n < nn){
      unsigned pack = (unsigned)hb[m][2*tid] | ((unsigned)hb[m][2*tid+1] << 16);
      hout[(size_t)n*256 + tid] = pack;
    }
  }
}

// ---- readout v3: 32 edges/block; coalesced LDS staging; (M32,N32) wave tiles;
//      m in registers; shuffle-butterfly flush. b1 pre-folded into h_l.
__global__ __launch_bounds__(256, 4) void k_readout3(
    const unsigned* __restrict__ hl, const unsigned* __restrict__ hp,
    const uint4* __restrict__ edgeL, const float* __restrict__ vvec,
    const unsigned short* __restrict__ w2t, const float* __restrict__ b2,
    const unsigned short* __restrict__ wmt, const float* __restrict__ bm,
    float* __restrict__ outw, unsigned* __restrict__ mmax){
  __shared__ __align__(16) char smem[33280];
  unsigned short (*hbuf)[520] = (unsigned short(*)[520])smem;   // dead after GEMM1
  unsigned short (*msb)[136]  = (unsigned short(*)[136])smem;   // aliases hbuf
  __shared__ int sidx[32], didx[32], bsh[32];
  __shared__ float dsts[32];
  int tid = threadIdx.x;
  int e0 = blockIdx.x*32;
  if (tid < 32){
    uint4 er = edgeL[e0 + tid];
    sidx[tid] = (int)er.x; didx[tid] = (int)er.y;
    dsts[tid] = __uint_as_float(er.z); bsh[tid] = (int)er.w;
  }
  __syncthreads();
  int j2 = tid*2;
  float2 vv = *(const float2*)&vvec[j2];
  #pragma unroll 4
  for (int i=0;i<32;i++){
    unsigned ua = hl[(size_t)sidx[i]*256 + tid];
    unsigned ub = hp[(size_t)didx[i]*256 + tid];
    float dd = dsts[i];
    float hx = fmaxf(bflo(ua) + bflo(ub) + dd*vv.x, 0.f);
    float hy = fmaxf(bfhi(ua) + bfhi(ub) + dd*vv.y, 0.f);
    *(unsigned*)&hbuf[i][j2] = (unsigned)f2bf(hx) | ((unsigned)f2bf(hy) << 16);
  }
  __syncthreads();
  int wave = tid >> 6, lane = tid & 63, quad = lane >> 4, l15 = lane & 15;
  int ns = wave*32;            // each wave: M=32 (all edges), N-strip of 32

  // GEMM1: m[32,128] = h[32,512] @ W2^T + b2
  float4v acc[2][2] = {{{0,0,0,0},{0,0,0,0}},{{0,0,0,0},{0,0,0,0}}};
  for (int k0 = 0; k0 < 512; k0 += 32){
    short8 A0 = *(const short8*)&hbuf[l15][k0 + quad*8];
    short8 A1 = *(const short8*)&hbuf[16 + l15][k0 + quad*8];
    short8 B0 = *(const short8*)&w2t[(size_t)(ns + l15)*512 + k0 + quad*8];
    short8 B1 = *(const short8*)&w2t[(size_t)(ns + 16 + l15)*512 + k0 + quad*8];
    acc[0][0] = __builtin_amdgcn_mfma_f32_16x16x32_bf16(A0, B0, acc[0][0], 0, 0, 0);
    acc[0][1] = __builtin_amdgcn_mfma_f32_16x16x32_bf16(A0, B1, acc[0][1], 0, 0, 0);
    acc[1][0] = __builtin_amdgcn_mfma_f32_16x16x32_bf16(A1, B0, acc[1][0], 0, 0, 0);
    acc[1][1] = __builtin_amdgcn_mfma_f32_16x16x32_bf16(A1, B1, acc[1][1], 0, 0, 0);
  }
  __syncthreads();   // all waves done reading hbuf; msb may overwrite
  float mreg[2][2][4];
  float b2c0 = b2[ns + l15], b2c1 = b2[ns + 16 + l15];
  #pragma unroll
  for (int mt=0;mt<2;mt++){
    #pragma unroll
    for (int nt=0;nt<2;nt++){
      float b2c = nt ? b2c1 : b2c0;
      int col = ns + nt*16 + l15;
      #pragma unroll
      for (int r=0;r<4;r++){
        float mv = acc[mt][nt][r] + b2c;
        mreg[mt][nt][r] = mv;
        msb[mt*16 + quad*4 + r][col] = f2bf(mv);
      }
    }
  }
  __syncthreads();

  // GEMM2: t = tanh(m@Wm^T + bm); flush sum(t*m), max(m) per batch
  float4v acc2[2][2] = {{{0,0,0,0},{0,0,0,0}},{{0,0,0,0},{0,0,0,0}}};
  for (int k0 = 0; k0 < 128; k0 += 32){
    short8 A0 = *(const short8*)&msb[l15][k0 + quad*8];
    short8 A1 = *(const short8*)&msb[16 + l15][k0 + quad*8];
    short8 B0 = *(const short8*)&wmt[(size_t)(ns + l15)*128 + k0 + quad*8];
    short8 B1 = *(const short8*)&wmt[(size_t)(ns + 16 + l15)*128 + k0 + quad*8];
    acc2[0][0] = __builtin_amdgcn_mfma_f32_16x16x32_bf16(A0, B0, acc2[0][0], 0, 0, 0);
    acc2[0][1] = __builtin_amdgcn_mfma_f32_16x16x32_bf16(A0, B1, acc2[0][1], 0, 0, 0);
    acc2[1][0] = __builtin_amdgcn_mfma_f32_16x16x32_bf16(A1, B0, acc2[1][0], 0, 0, 0);
    acc2[1][1] = __builtin_amdgcn_mfma_f32_16x16x32_bf16(A1, B1, acc2[1][1], 0, 0, 0);
  }
  float bm0 = bm[ns + l15], bm1 = bm[ns + 16 + l15];
  bool uni = (bsh[0] == bsh[31]);
  int b0 = bsh[0];
  #pragma unroll
  for (int nt=0;nt<2;nt++){
    int col = ns + nt*16 + l15;
    float bmc = nt ? bm1 : bm0;
    if (uni){
      float s = 0.f, mx = -3.402823466e38f;
      #pragma unroll
      for (int mt=0;mt<2;mt++){
        #pragma unroll
        for (int r=0;r<4;r++){
          float mv = mreg[mt][nt][r];
          float t = tanh_fast(acc2[mt][nt][r] + bmc);
          s += t*mv; mx = fmaxf(mx, mv);
        }
      }
      s += __shfl_xor(s, 16); s += __shfl_xor(s, 32);
      mx = fmaxf(mx, __shfl_xor(mx, 16)); mx = fmaxf(mx, __shfl_xor(mx, 32));
      if (quad == 0){
        atomicAdd(&outw[b0*256 + col], s);
        atomicMax(&mmax[b0*128 + col], encf(mx));
      }
    } else {
      #pragma unroll
      for (int mt=0;mt<2;mt++){
        #pragma unroll
        for (int r=0;r<4;r++){
          int row = mt*16 + quad*4 + r;
          int b = bsh[row];
          float mv = mreg[mt][nt][r];
          float t = tanh_fast(acc2[mt][nt][r] + bmc);
          atomicAdd(&outw[b*256 + col], t*mv);
          atomicMax(&mmax[b*128 + col], encf(mv));
        }
      }
    }
  }
}

__global__ __launch_bounds__(256) void k_final(const unsigned* __restrict__ mmax,
    float* __restrict__ out){
  int gid = blockIdx.x*256 + threadIdx.x;   // 32768 = 256*128
  unsigned enc = mmax[gid];
  float v;
  if (enc == 0u) v = 0.f;
  else if (enc & 0x80000000u) v = __uint_as_float(enc & 0x7FFFFFFFu);
  else v = __uint_as_float(~enc);
  int g = gid >> 7, cc = gid & 127;
  out[g*256 + 128 + cc] = v;
}

extern "C" void kernel_launch(void* const* d_in, const int* in_sizes, int n_in,
                              void* d_out, int out_size, void* d_ws, size_t ws_size,
                              hipStream_t stream) {
  const float* x_l    = (const float*)d_in[0];
  const float* x_p    = (const float*)d_in[1];
  const float* ea     = (const float*)d_in[2];
  const int*   esrc   = (const int*)d_in[3];
  const int*   edst   = (const int*)d_in[4];
  const int*   lbatch = (const int*)d_in[5];
  const float* W_node = (const float*)d_in[6];
  const float* W_el   = (const float*)d_in[7];
  const float* Wb     = (const float*)d_in[8];
  const float* bb     = (const float*)d_in[9];
  const float* Wn     = (const float*)d_in[10];
  const float* Ws     = (const float*)d_in[11];
  const float* bconv  = (const float*)d_in[12];
  const float* W1     = (const float*)d_in[13];
  const float* b1     = (const float*)d_in[14];
  const float* W2     = (const float*)d_in[15];
  const float* b2     = (const float*)d_in[16];
  const float* Wm     = (const float*)d_in[17];
  const float* bm     = (const float*)d_in[18];

  // ---- workspace layout (decimal offsets), peak < 256 MiB ----
  char* w = (char*)d_ws;
  unsigned short* xl0 = (unsigned short*)(w + 0);
  unsigned short* xl1 = (unsigned short*)(w + 12800000);
  unsigned short* xp0 = (unsigned short*)(w + 25600000);
  unsigned short* xp1 = (unsigned short*)(w + 64000000);
  int*      srcP  = (int*)(w + 102400000);
  uint4*    rbfP  = (uint4*)(w + 104400000);
  uint4*    rbfL  = (uint4*)(w + 112400000);
  unsigned* h_l   = (unsigned*)(w + 0);
  unsigned* h_p   = (unsigned*)(w + 51200000);
  unsigned short* xl_s = (unsigned short*)(w + 204800000);
  unsigned short* xp_s = (unsigned short*)(w + 217600000);
  unsigned short* wcat = (unsigned short*)(w + 256000000);
  unsigned short* w1t  = (unsigned short*)(w + 256393216);
  unsigned short* w2t  = (unsigned short*)(w + 256655360);
  unsigned short* wmt  = (unsigned short*)(w + 256786432);
  float*    vvec  = (float*)(w + 256819200);
  unsigned* mmax  = (unsigned*)(w + 256821248);
  unsigned* bsumL = (unsigned*)(w + 256952320);
  unsigned* bsumP = (unsigned*)(w + 256953344);
  unsigned* rowptrL = (unsigned*)(w + 256954368);
  unsigned* cursorL = (unsigned*)(w + 257154432);
  unsigned* rowptrP = (unsigned*)(w + 257354432);
  unsigned* cursorP = (unsigned*)(w + 257954496);
  unsigned* cntL    = (unsigned*)(w + 258554496);
  unsigned* cntP    = (unsigned*)(w + 258754496);
  uint4*    edgeL   = (uint4*)(w + 259354496);   // {src, dst, bits(d), batch}

  float* out = (float*)d_out;

  k_zero<<<1024, 256, 0, stream>>>((unsigned*)(w + 204800000), 51200000/4);  // xl_s+xp_s
  k_zero<<<196, 256, 0, stream>>>((unsigned*)(w + 258554496), 800000/4);     // cntL+cntP
  k_zero<<<128, 256, 0, stream>>>(mmax, 131072/4);
  k_zero<<<256, 256, 0, stream>>>((unsigned*)d_out, 262144/4);

  k_embed<<<25000, 256, 0, stream>>>(x_l, W_node, xl0);
  k_embed<<<75000, 256, 0, stream>>>(x_p, W_node, xp0);
  k_vvec<<<2, 256, 0, stream>>>(W_el, W1, vvec);
  k_w2t<<<256, 256, 0, stream>>>(W2, w2t);
  k_wmt<<<64, 256, 0, stream>>>(Wm, wmt);
  k_wcat<<<768, 256, 0, stream>>>(Ws, Wn, wcat);
  k_w1t<<<512, 256, 0, stream>>>(W1, w1t);

  k_count<<<1954, 256, 0, stream>>>(esrc, edst, cntL, cntP);
  k_chunkscan<<<49, 256, 0, stream>>>(cntL, rowptrL, bsumL, NLn);
  k_chunkscan<<<147, 256, 0, stream>>>(cntP, rowptrP, bsumP, NPn);
  k_scanb<<<1, 256, 0, stream>>>(bsumL, 49);
  k_scanb<<<1, 256, 0, stream>>>(bsumP, 147);
  k_addoff<<<196, 256, 0, stream>>>(rowptrL, cursorL, bsumL, NLn);
  k_addoff<<<586, 256, 0, stream>>>(rowptrP, cursorP, bsumP, NPn);
  k_place<<<1954, 256, 0, stream>>>(esrc, edst, ea, lbatch, cursorL, cursorP,
                                    edgeL, rbfL, srcP, rbfP);

  unsigned short *xlc = xl0, *xln = xl1, *xpc = xp0, *xpn = xp1;
  for (int l = 0; l < 3; ++l){
    int ilp = 2*l, ipl = 2*l + 1;
    k_conv<<<4688, 256, 0, stream>>>(xpc, xlc, rowptrP, srcP, 1, rbfP,
        Wb + ilp*1024, bb + ilp*128, wcat + ilp*32768, bconv + ilp*128,
        xpn, xp_s, NPn);
    k_conv<<<1563, 256, 0, stream>>>(xlc, xpc, rowptrL, (const int*)edgeL + 1, 4, rbfL,
        Wb + ipl*1024, bb + ipl*128, wcat + ipl*32768, bconv + ipl*128,
        xln, xl_s, NLn);
    unsigned short* t;
    t = xlc; xlc = xln; xln = t;
    t = xpc; xpc = xpn; xpn = t;
  }

  // b1 folded into h_l here (bias arg); protein part gets no bias
  k_hproj_mfma<<<1563, 256, 0, stream>>>(xl_s, w1t, b1, h_l, NLn);
  k_hproj_mfma<<<4688, 256, 0, stream>>>(xp_s, w1t + 65536, nullptr, h_p, NPn);

  k_readout3<<<En/32, 256, 0, stream>>>(h_l, h_p, edgeL, vvec,
                                        w2t, b2, wmt, bm, out, mmax);
  k_final<<<128, 256, 0, stream>>>(mmax, out);
}

// Round 7
// 2162.402 us; speedup vs baseline: 1.9083x; 1.0295x over previous
//
#include <hip/hip_runtime.h>
#include <hip/hip_bf16.h>

// HeteroNet on MI355X — round 7.
// R6: 2226us total; readout 349us (healthy); conv phase ~1600us dominant.
// Conv fix: LDS-staged edge indices (gather chain 2-deep -> 1-deep), unroll-4
// aggregation (4 outstanding gathers), both directions fused per layer.
// Readout: staging unroll 8.

#define NLn 50000
#define NPn 150000
#define En  500000
#define NBP 4688   // ceil(NPn/32)
#define NBL 1563   // ceil(NLn/32)

typedef __attribute__((ext_vector_type(8))) short short8;
typedef __attribute__((ext_vector_type(4))) float float4v;

__device__ __forceinline__ float bf2f(unsigned short u){ return __uint_as_float(((unsigned)u) << 16); }
__device__ __forceinline__ float bflo(unsigned u){ return __uint_as_float(u << 16); }
__device__ __forceinline__ float bfhi(unsigned u){ return __uint_as_float(u & 0xffff0000u); }
__device__ __forceinline__ unsigned short f2bf(float f){
  __hip_bfloat16 h = __float2bfloat16(f);
  return *reinterpret_cast<unsigned short*>(&h);
}
// order-preserving float->uint; enc(v)>0 for all finite v, so 0 == "empty segment"
__device__ __forceinline__ unsigned encf(float f){
  unsigned u = __float_as_uint(f);
  return (u & 0x80000000u) ? ~u : (u | 0x80000000u);
}
__device__ __forceinline__ float tanh_fast(float x){
  return 1.f - 2.f/(__expf(2.f*x) + 1.f);
}
// base = silu(rbf@Wb + bb) for one channel, rbf packed bf16x8
__device__ __forceinline__ float silu_rbf(uint4 rp, const float* wb, float bbc){
  const unsigned short* rs = (const unsigned short*)&rp;
  float s = bbc;
  #pragma unroll
  for (int j=0;j<8;j++) s += bf2f(rs[j])*wb[j];
  return s / (1.f + __expf(-s));
}

__global__ __launch_bounds__(256) void k_zero(unsigned* __restrict__ p, long n){
  long i = (long)blockIdx.x*256 + threadIdx.x;
  long stride = (long)gridDim.x*256;
  for (; i < n; i += stride) p[i] = 0u;
}

// out[n,c] = sum_k X[n,k]*W[k,c]  ([N,44]@[44,128]) -> bf16
__global__ __launch_bounds__(256) void k_embed(const float* __restrict__ X,
    const float* __restrict__ Wn, unsigned short* __restrict__ out){
  int gid = blockIdx.x*256 + threadIdx.x;
  int n = gid >> 7, c = gid & 127;
  const float* xr = X + (size_t)n*44;
  float acc = 0.f;
  #pragma unroll
  for (int k=0;k<44;k++) acc += xr[k]*Wn[k*128+c];
  out[(size_t)n*128 + c] = f2bf(acc);
}

// v[j] = sum_r W_el[r] * W1[(256+r)*512 + j]
__global__ void k_vvec(const float* __restrict__ Wel, const float* __restrict__ W1,
                       float* __restrict__ v){
  int j = blockIdx.x*256 + threadIdx.x;
  if (j >= 512) return;
  float s = 0.f;
  #pragma unroll
  for (int r=0;r<8;r++) s += Wel[r]*W1[(256+r)*512 + j];
  v[j] = s;
}

// w2t[n][k] = bf16(W2[k][n])   (512x128 -> 128x512)
__global__ __launch_bounds__(256) void k_w2t(const float* __restrict__ W2,
    unsigned short* __restrict__ w2t){
  int gid = blockIdx.x*256 + threadIdx.x;   // 65536
  int n = gid >> 9, k = gid & 511;
  w2t[n*512 + k] = f2bf(W2[k*128 + n]);
}
// wmt[n][k] = bf16(Wm[k][n])   (128x128)
__global__ __launch_bounds__(256) void k_wmt(const float* __restrict__ Wm,
    unsigned short* __restrict__ wmt){
  int gid = blockIdx.x*256 + threadIdx.x;   // 16384
  int n = gid >> 7, k = gid & 127;
  wmt[n*128 + k] = f2bf(Wm[k*128 + n]);
}
// wcat[i][n][k] = bf16( k<128 ? Ws[i][k][n] : Wn[i][k-128][n] )   (6x128x256)
__global__ __launch_bounds__(256) void k_wcat(const float* __restrict__ Ws,
    const float* __restrict__ Wn, unsigned short* __restrict__ wcat){
  int gid = blockIdx.x*256 + threadIdx.x;   // 196608
  int i = gid >> 15, rem = gid & 32767;
  int n = rem >> 8, k = rem & 255;
  float v = (k < 128) ? Ws[i*16384 + k*128 + n] : Wn[i*16384 + (k-128)*128 + n];
  wcat[gid] = f2bf(v);
}
// w1t[part][n][k] = bf16(W1[part*128+k][n])
__global__ __launch_bounds__(256) void k_w1t(const float* __restrict__ W1,
    unsigned short* __restrict__ w1t){
  int gid = blockIdx.x*256 + threadIdx.x;   // 131072 = 2*512*128
  int part = gid >> 16, rem = gid & 65535;
  int n = rem >> 7, k = rem & 127;
  w1t[gid] = f2bf(W1[(part*128 + k)*512 + n]);
}

// ---- CSR construction ----
__global__ __launch_bounds__(256) void k_count(const int* __restrict__ esrc,
    const int* __restrict__ edst, unsigned* __restrict__ cntL, unsigned* __restrict__ cntP){
  int e = blockIdx.x*256 + threadIdx.x;
  if (e >= En) return;
  atomicAdd(&cntL[esrc[e]], 1u);
  atomicAdd(&cntP[edst[e]], 1u);
}
__global__ __launch_bounds__(256) void k_chunkscan(const unsigned* __restrict__ cnt,
    unsigned* __restrict__ rowptr, unsigned* __restrict__ bsum, int n){
  __shared__ unsigned ts[256];
  int tid = threadIdx.x;
  int base = blockIdx.x*1024 + tid*4;
  unsigned v[4], run = 0;
  #pragma unroll
  for (int j=0;j<4;j++){ v[j] = run; run += (base+j < n) ? cnt[base+j] : 0u; }
  ts[tid] = run; __syncthreads();
  for (int off=1; off<256; off<<=1){
    unsigned t = (tid>=off) ? ts[tid-off] : 0u; __syncthreads();
    ts[tid] += t; __syncthreads();
  }
  unsigned excl = ts[tid] - run;
  #pragma unroll
  for (int j=0;j<4;j++) if (base+j < n) rowptr[base+j] = excl + v[j];
  if (tid == 255) bsum[blockIdx.x] = ts[255];
}
__global__ void k_scanb(unsigned* __restrict__ bsum, int nc){
  __shared__ unsigned ts[256];
  int tid = threadIdx.x;
  unsigned x = (tid < nc) ? bsum[tid] : 0u;
  ts[tid] = x; __syncthreads();
  for (int off=1; off<256; off<<=1){
    unsigned t = (tid>=off) ? ts[tid-off] : 0u; __syncthreads();
    ts[tid] += t; __syncthreads();
  }
  if (tid < nc) bsum[tid] = ts[tid] - x;
}
__global__ __launch_bounds__(256) void k_addoff(unsigned* __restrict__ rowptr,
    unsigned* __restrict__ cursor, const unsigned* __restrict__ bsum, int n){
  int i = blockIdx.x*256 + threadIdx.x;
  if (i < n){
    unsigned r = rowptr[i] + bsum[i>>10];
    rowptr[i] = r; cursor[i] = r;
  }
  if (i == 0) rowptr[n] = En;
}
__global__ __launch_bounds__(256) void k_place(const int* __restrict__ esrc,
    const int* __restrict__ edst, const float* __restrict__ ea,
    const int* __restrict__ lbatch, unsigned* __restrict__ curL,
    unsigned* __restrict__ curP, uint4* __restrict__ edgeL,
    uint4* __restrict__ rbfL, int* __restrict__ srcP, uint4* __restrict__ rbfP){
  int e = blockIdx.x*256 + threadIdx.x;
  if (e >= En) return;
  int s = esrc[e], d = edst[e];
  float dd = ea[e];
  unsigned short r[8];
  #pragma unroll
  for (int j=0;j<8;j++){
    float a = (dd - 0.7142857143f*(float)j) * 1.6f;   // mu=linspace(0,5,8), sigma=5/8
    r[j] = f2bf(__expf(-a*a));
  }
  uint4 rp;
  rp.x = (unsigned)r[0] | ((unsigned)r[1]<<16);
  rp.y = (unsigned)r[2] | ((unsigned)r[3]<<16);
  rp.z = (unsigned)r[4] | ((unsigned)r[5]<<16);
  rp.w = (unsigned)r[6] | ((unsigned)r[7]<<16);
  unsigned pl = atomicAdd(&curL[s], 1u);
  uint4 er; er.x = (unsigned)s; er.y = (unsigned)d;
  er.z = __float_as_uint(dd); er.w = (unsigned)lbatch[s];
  edgeL[pl] = er; rbfL[pl] = rp;
  unsigned pp = atomicAdd(&curP[d], 1u);
  srcP[pp] = s; rbfP[pp] = rp;
}

// ---- fused dual-direction conv: LDS-staged edge ids, unroll-4 aggregate, MFMA update
// blocks [0,NBP): dst=protein (gather ligand); [NBP,NBP+NBL): dst=ligand (gather protein)
#define EDGE_CAP 1024
__global__ __launch_bounds__(256) void k_conv2(
    const unsigned short* __restrict__ xp_in, const unsigned short* __restrict__ xl_in,
    unsigned short* __restrict__ xp_out, unsigned short* __restrict__ xl_out,
    unsigned short* __restrict__ xp_sum, unsigned short* __restrict__ xl_sum,
    const unsigned* __restrict__ rowptrP, const int* __restrict__ srcP,
    const uint4* __restrict__ rbfP,
    const unsigned* __restrict__ rowptrL, const int* __restrict__ dstL,
    const uint4* __restrict__ rbfL,
    const float* __restrict__ Wb_lp, const float* __restrict__ bb_lp,
    const unsigned short* __restrict__ wcat_lp, const float* __restrict__ bias_lp,
    const float* __restrict__ Wb_pl, const float* __restrict__ bb_pl,
    const unsigned short* __restrict__ wcat_pl, const float* __restrict__ bias_pl){
  __shared__ unsigned short ab[32][264];   // [m][k]: k<128 x_dst, k>=128 agg (bf16)
  __shared__ float ob[32][132];
  __shared__ int snb[EDGE_CAP];
  __shared__ unsigned rps[33];
  int tid = threadIdx.x, c = tid & 127, hh = tid >> 7;
  bool isP = blockIdx.x < NBP;
  const unsigned short* xdst_in = isP ? xp_in : xl_in;
  const unsigned short* xsrc_in = isP ? xl_in : xp_in;
  unsigned short* xout = isP ? xp_out : xl_out;
  unsigned short* xsum = isP ? xp_sum : xl_sum;
  const unsigned* rowptr = isP ? rowptrP : rowptrL;
  const int* eidx = isP ? srcP : dstL;
  int estride = isP ? 1 : 4;
  const uint4* rbfpk = isP ? rbfP : rbfL;
  const float* Wb_i = isP ? Wb_lp : Wb_pl;
  const float* bb_i = isP ? bb_lp : bb_pl;
  const unsigned short* wcat = isP ? wcat_lp : wcat_pl;
  const float* bias = isP ? bias_lp : bias_pl;
  int ndst = isP ? NPn : NLn;
  int n0 = (isP ? blockIdx.x : (blockIdx.x - NBP)) * 32;

  if (tid < 33){
    int idx = n0 + tid; if (idx > ndst) idx = ndst;
    rps[tid] = rowptr[idx];
  }
  float wb[8];
  #pragma unroll
  for (int j=0;j<8;j++) wb[j] = Wb_i[j*128 + c];
  float bbc = bb_i[c];
  __syncthreads();
  int r00 = (int)rps[0], rEnd = (int)rps[32];
  int eblk = rEnd - r00;
  bool fits = (eblk <= EDGE_CAP);
  if (fits){
    for (int p = tid; p < eblk; p += 256) snb[p] = eidx[(size_t)(r00+p)*estride];
  }
  __syncthreads();

  for (int m = hh*16; m < hh*16+16; m++){
    int n = n0 + m;
    float a0=0.f, a1=0.f, a2=0.f, a3=0.f;
    int dg = 1;
    if (n < ndst){
      ab[m][c] = xdst_in[(size_t)n*128 + c];
      int r0 = (int)rps[m], r1 = (int)rps[m+1];
      dg = r1 - r0;
      int p = r0;
      for (; p + 3 < r1; p += 4){
        int s0,s1,s2,s3;
        if (fits){
          s0 = snb[p-r00]; s1 = snb[p-r00+1]; s2 = snb[p-r00+2]; s3 = snb[p-r00+3];
        } else {
          s0 = eidx[(size_t)p*estride];     s1 = eidx[(size_t)(p+1)*estride];
          s2 = eidx[(size_t)(p+2)*estride]; s3 = eidx[(size_t)(p+3)*estride];
        }
        float b0 = silu_rbf(rbfpk[p],   wb, bbc);
        float b1v = silu_rbf(rbfpk[p+1], wb, bbc);
        float b2v = silu_rbf(rbfpk[p+2], wb, bbc);
        float b3v = silu_rbf(rbfpk[p+3], wb, bbc);
        a0 += b0  * bf2f(xsrc_in[(size_t)s0*128 + c]);
        a1 += b1v * bf2f(xsrc_in[(size_t)s1*128 + c]);
        a2 += b2v * bf2f(xsrc_in[(size_t)s2*128 + c]);
        a3 += b3v * bf2f(xsrc_in[(size_t)s3*128 + c]);
      }
      for (; p < r1; p++){
        int s0 = fits ? snb[p-r00] : eidx[(size_t)p*estride];
        float b0 = silu_rbf(rbfpk[p], wb, bbc);
        a0 += b0 * bf2f(xsrc_in[(size_t)s0*128 + c]);
      }
    } else {
      ab[m][c] = 0;
    }
    float inv = 1.f / (float)(dg > 1 ? dg : 1);
    ab[m][128 + c] = f2bf(((a0+a1)+(a2+a3)) * inv);
  }
  __syncthreads();

  int wave = tid >> 6, lane = tid & 63, quad = lane >> 4, l15 = lane & 15;
  int mt = wave & 1, nh = wave >> 1;
  int arow = mt*16 + l15;
  float4v acc[4] = {{0,0,0,0},{0,0,0,0},{0,0,0,0},{0,0,0,0}};
  for (int k0 = 0; k0 < 256; k0 += 32){
    short8 A = *(const short8*)&ab[arow][k0 + quad*8];
    #pragma unroll
    for (int nt=0;nt<4;nt++){
      short8 B = *(const short8*)&wcat[(size_t)(nh*64 + nt*16 + l15)*256 + k0 + quad*8];
      acc[nt] = __builtin_amdgcn_mfma_f32_16x16x32_bf16(A, B, acc[nt], 0, 0, 0);
    }
  }
  #pragma unroll
  for (int nt=0;nt<4;nt++){
    int col = nh*64 + nt*16 + l15;
    float bc = bias[col];
    #pragma unroll
    for (int r=0;r<4;r++){
      int row = mt*16 + quad*4 + r;
      float v = acc[nt][r] + bc;
      ob[row][col] = (v > 0.f) ? v : 0.01f*v;         // leaky_relu
    }
  }
  __syncthreads();
  for (int m = hh*16; m < hh*16+16; m++){
    int n = n0 + m;
    if (n < ndst){
      float v = ob[m][c];
      size_t off = (size_t)n*128 + c;
      xout[off] = f2bf(v);
      xsum[off] = f2bf(bf2f(xsum[off]) + v);
    }
  }
}

// ---- MFMA hproj: h[n][512] = xsum[n][128] @ w1t^T (+ optional bias), 32 nodes/blk
__global__ __launch_bounds__(256) void k_hproj_mfma(
    const unsigned short* __restrict__ xs, const unsigned short* __restrict__ w1t,
    const float* __restrict__ bias, unsigned* __restrict__ hout, int nn){
  __shared__ unsigned short hb[32][528];
  int tid = threadIdx.x;
  int wave = tid >> 6, lane = tid & 63, quad = lane >> 4, l15 = lane & 15;
  int mt = wave & 1, nh = wave >> 1;
  int n0 = blockIdx.x*32;
  int an = n0 + mt*16 + l15; if (an >= nn) an = nn - 1;
  const unsigned short* aptr = xs + (size_t)an*128;
  float4v acc[16];
  #pragma unroll
  for (int i=0;i<16;i++) acc[i] = (float4v){0,0,0,0};
  for (int k0 = 0; k0 < 128; k0 += 32){
    short8 A = *(const short8*)&aptr[k0 + quad*8];
    #pragma unroll
    for (int nt=0;nt<16;nt++){
      short8 B = *(const short8*)&w1t[(size_t)(nh*256 + nt*16 + l15)*128 + k0 + quad*8];
      acc[nt] = __builtin_amdgcn_mfma_f32_16x16x32_bf16(A, B, acc[nt], 0, 0, 0);
    }
  }
  #pragma unroll
  for (int nt=0;nt<16;nt++){
    int col = nh*256 + nt*16 + l15;
    float bv = bias ? bias[col] : 0.f;
    #pragma unroll
    for (int r=0;r<4;r++) hb[mt*16 + quad*4 + r][col] = f2bf(acc[nt][r] + bv);
  }
  __syncthreads();
  for (int m=0;m<32;m++){
    int n = n0 + m;
    if (n < nn){
      unsigned pack = (unsigned)hb[m][2*tid] | ((unsigned)hb[m][2*tid+1] << 16);
      hout[(size_t)n*256 + tid] = pack;
    }
  }
}

// ---- readout v3: 32 edges/block; coalesced LDS staging; (M32,N32) wave tiles;
//      m in registers; shuffle-butterfly flush. b1 pre-folded into h_l.
__global__ __launch_bounds__(256, 4) void k_readout3(
    const unsigned* __restrict__ hl, const unsigned* __restrict__ hp,
    const uint4* __restrict__ edgeL, const float* __restrict__ vvec,
    const unsigned short* __restrict__ w2t, const float* __restrict__ b2,
    const unsigned short* __restrict__ wmt, const float* __restrict__ bm,
    float* __restrict__ outw, unsigned* __restrict__ mmax){
  __shared__ __align__(16) char smem[33280];
  unsigned short (*hbuf)[520] = (unsigned short(*)[520])smem;   // dead after GEMM1
  unsigned short (*msb)[136]  = (unsigned short(*)[136])smem;   // aliases hbuf
  __shared__ int sidx[32], didx[32], bsh[32];
  __shared__ float dsts[32];
  int tid = threadIdx.x;
  int e0 = blockIdx.x*32;
  if (tid < 32){
    uint4 er = edgeL[e0 + tid];
    sidx[tid] = (int)er.x; didx[tid] = (int)er.y;
    dsts[tid] = __uint_as_float(er.z); bsh[tid] = (int)er.w;
  }
  __syncthreads();
  int j2 = tid*2;
  float2 vv = *(const float2*)&vvec[j2];
  #pragma unroll 8
  for (int i=0;i<32;i++){
    unsigned ua = hl[(size_t)sidx[i]*256 + tid];
    unsigned ub = hp[(size_t)didx[i]*256 + tid];
    float dd = dsts[i];
    float hx = fmaxf(bflo(ua) + bflo(ub) + dd*vv.x, 0.f);
    float hy = fmaxf(bfhi(ua) + bfhi(ub) + dd*vv.y, 0.f);
    *(unsigned*)&hbuf[i][j2] = (unsigned)f2bf(hx) | ((unsigned)f2bf(hy) << 16);
  }
  __syncthreads();
  int wave = tid >> 6, lane = tid & 63, quad = lane >> 4, l15 = lane & 15;
  int ns = wave*32;            // each wave: M=32 (all edges), N-strip of 32

  // GEMM1: m[32,128] = h[32,512] @ W2^T + b2
  float4v acc[2][2] = {{{0,0,0,0},{0,0,0,0}},{{0,0,0,0},{0,0,0,0}}};
  for (int k0 = 0; k0 < 512; k0 += 32){
    short8 A0 = *(const short8*)&hbuf[l15][k0 + quad*8];
    short8 A1 = *(const short8*)&hbuf[16 + l15][k0 + quad*8];
    short8 B0 = *(const short8*)&w2t[(size_t)(ns + l15)*512 + k0 + quad*8];
    short8 B1 = *(const short8*)&w2t[(size_t)(ns + 16 + l15)*512 + k0 + quad*8];
    acc[0][0] = __builtin_amdgcn_mfma_f32_16x16x32_bf16(A0, B0, acc[0][0], 0, 0, 0);
    acc[0][1] = __builtin_amdgcn_mfma_f32_16x16x32_bf16(A0, B1, acc[0][1], 0, 0, 0);
    acc[1][0] = __builtin_amdgcn_mfma_f32_16x16x32_bf16(A1, B0, acc[1][0], 0, 0, 0);
    acc[1][1] = __builtin_amdgcn_mfma_f32_16x16x32_bf16(A1, B1, acc[1][1], 0, 0, 0);
  }
  __syncthreads();   // all waves done reading hbuf; msb may overwrite
  float mreg[2][2][4];
  float b2c0 = b2[ns + l15], b2c1 = b2[ns + 16 + l15];
  #pragma unroll
  for (int mt=0;mt<2;mt++){
    #pragma unroll
    for (int nt=0;nt<2;nt++){
      float b2c = nt ? b2c1 : b2c0;
      int col = ns + nt*16 + l15;
      #pragma unroll
      for (int r=0;r<4;r++){
        float mv = acc[mt][nt][r] + b2c;
        mreg[mt][nt][r] = mv;
        msb[mt*16 + quad*4 + r][col] = f2bf(mv);
      }
    }
  }
  __syncthreads();

  // GEMM2: t = tanh(m@Wm^T + bm); flush sum(t*m), max(m) per batch
  float4v acc2[2][2] = {{{0,0,0,0},{0,0,0,0}},{{0,0,0,0},{0,0,0,0}}};
  for (int k0 = 0; k0 < 128; k0 += 32){
    short8 A0 = *(const short8*)&msb[l15][k0 + quad*8];
    short8 A1 = *(const short8*)&msb[16 + l15][k0 + quad*8];
    short8 B0 = *(const short8*)&wmt[(size_t)(ns + l15)*128 + k0 + quad*8];
    short8 B1 = *(const short8*)&wmt[(size_t)(ns + 16 + l15)*128 + k0 + quad*8];
    acc2[0][0] = __builtin_amdgcn_mfma_f32_16x16x32_bf16(A0, B0, acc2[0][0], 0, 0, 0);
    acc2[0][1] = __builtin_amdgcn_mfma_f32_16x16x32_bf16(A0, B1, acc2[0][1], 0, 0, 0);
    acc2[1][0] = __builtin_amdgcn_mfma_f32_16x16x32_bf16(A1, B0, acc2[1][0], 0, 0, 0);
    acc2[1][1] = __builtin_amdgcn_mfma_f32_16x16x32_bf16(A1, B1, acc2[1][1], 0, 0, 0);
  }
  float bm0 = bm[ns + l15], bm1 = bm[ns + 16 + l15];
  bool uni = (bsh[0] == bsh[31]);
  int b0 = bsh[0];
  #pragma unroll
  for (int nt=0;nt<2;nt++){
    int col = ns + nt*16 + l15;
    float bmc = nt ? bm1 : bm0;
    if (uni){
      float s = 0.f, mx = -3.402823466e38f;
      #pragma unroll
      for (int mt=0;mt<2;mt++){
        #pragma unroll
        for (int r=0;r<4;r++){
          float mv = mreg[mt][nt][r];
          float t = tanh_fast(acc2[mt][nt][r] + bmc);
          s += t*mv; mx = fmaxf(mx, mv);
        }
      }
      s += __shfl_xor(s, 16); s += __shfl_xor(s, 32);
      mx = fmaxf(mx, __shfl_xor(mx, 16)); mx = fmaxf(mx, __shfl_xor(mx, 32));
      if (quad == 0){
        atomicAdd(&outw[b0*256 + col], s);
        atomicMax(&mmax[b0*128 + col], encf(mx));
      }
    } else {
      #pragma unroll
      for (int mt=0;mt<2;mt++){
        #pragma unroll
        for (int r=0;r<4;r++){
          int row = mt*16 + quad*4 + r;
          int b = bsh[row];
          float mv = mreg[mt][nt][r];
          float t = tanh_fast(acc2[mt][nt][r] + bmc);
          atomicAdd(&outw[b*256 + col], t*mv);
          atomicMax(&mmax[b*128 + col], encf(mv));
        }
      }
    }
  }
}

__global__ __launch_bounds__(256) void k_final(const unsigned* __restrict__ mmax,
    float* __restrict__ out){
  int gid = blockIdx.x*256 + threadIdx.x;   // 32768 = 256*128
  unsigned enc = mmax[gid];
  float v;
  if (enc == 0u) v = 0.f;
  else if (enc & 0x80000000u) v = __uint_as_float(enc & 0x7FFFFFFFu);
  else v = __uint_as_float(~enc);
  int g = gid >> 7, cc = gid & 127;
  out[g*256 + 128 + cc] = v;
}

extern "C" void kernel_launch(void* const* d_in, const int* in_sizes, int n_in,
                              void* d_out, int out_size, void* d_ws, size_t ws_size,
                              hipStream_t stream) {
  const float* x_l    = (const float*)d_in[0];
  const float* x_p    = (const float*)d_in[1];
  const float* ea     = (const float*)d_in[2];
  const int*   esrc   = (const int*)d_in[3];
  const int*   edst   = (const int*)d_in[4];
  const int*   lbatch = (const int*)d_in[5];
  const float* W_node = (const float*)d_in[6];
  const float* W_el   = (const float*)d_in[7];
  const float* Wb     = (const float*)d_in[8];
  const float* bb     = (const float*)d_in[9];
  const float* Wn     = (const float*)d_in[10];
  const float* Ws     = (const float*)d_in[11];
  const float* bconv  = (const float*)d_in[12];
  const float* W1     = (const float*)d_in[13];
  const float* b1     = (const float*)d_in[14];
  const float* W2     = (const float*)d_in[15];
  const float* b2     = (const float*)d_in[16];
  const float* Wm     = (const float*)d_in[17];
  const float* bm     = (const float*)d_in[18];

  // ---- workspace layout (decimal offsets), peak < 256 MiB ----
  char* w = (char*)d_ws;
  unsigned short* xl0 = (unsigned short*)(w + 0);
  unsigned short* xl1 = (unsigned short*)(w + 12800000);
  unsigned short* xp0 = (unsigned short*)(w + 25600000);
  unsigned short* xp1 = (unsigned short*)(w + 64000000);
  int*      srcP  = (int*)(w + 102400000);
  uint4*    rbfP  = (uint4*)(w + 104400000);
  uint4*    rbfL  = (uint4*)(w + 112400000);
  unsigned* h_l   = (unsigned*)(w + 0);
  unsigned* h_p   = (unsigned*)(w + 51200000);
  unsigned short* xl_s = (unsigned short*)(w + 204800000);
  unsigned short* xp_s = (unsigned short*)(w + 217600000);
  unsigned short* wcat = (unsigned short*)(w + 256000000);
  unsigned short* w1t  = (unsigned short*)(w + 256393216);
  unsigned short* w2t  = (unsigned short*)(w + 256655360);
  unsigned short* wmt  = (unsigned short*)(w + 256786432);
  float*    vvec  = (float*)(w + 256819200);
  unsigned* mmax  = (unsigned*)(w + 256821248);
  unsigned* bsumL = (unsigned*)(w + 256952320);
  unsigned* bsumP = (unsigned*)(w + 256953344);
  unsigned* rowptrL = (unsigned*)(w + 256954368);
  unsigned* cursorL = (unsigned*)(w + 257154432);
  unsigned* rowptrP = (unsigned*)(w + 257354432);
  unsigned* cursorP = (unsigned*)(w + 257954496);
  unsigned* cntL    = (unsigned*)(w + 258554496);
  unsigned* cntP    = (unsigned*)(w + 258754496);
  uint4*    edgeL   = (uint4*)(w + 259354496);   // {src, dst, bits(d), batch}

  float* out = (float*)d_out;

  k_zero<<<1024, 256, 0, stream>>>((unsigned*)(w + 204800000), 51200000/4);  // xl_s+xp_s
  k_zero<<<196, 256, 0, stream>>>((unsigned*)(w + 258554496), 800000/4);     // cntL+cntP
  k_zero<<<128, 256, 0, stream>>>(mmax, 131072/4);
  k_zero<<<256, 256, 0, stream>>>((unsigned*)d_out, 262144/4);

  k_embed<<<25000, 256, 0, stream>>>(x_l, W_node, xl0);
  k_embed<<<75000, 256, 0, stream>>>(x_p, W_node, xp0);
  k_vvec<<<2, 256, 0, stream>>>(W_el, W1, vvec);
  k_w2t<<<256, 256, 0, stream>>>(W2, w2t);
  k_wmt<<<64, 256, 0, stream>>>(Wm, wmt);
  k_wcat<<<768, 256, 0, stream>>>(Ws, Wn, wcat);
  k_w1t<<<512, 256, 0, stream>>>(W1, w1t);

  k_count<<<1954, 256, 0, stream>>>(esrc, edst, cntL, cntP);
  k_chunkscan<<<49, 256, 0, stream>>>(cntL, rowptrL, bsumL, NLn);
  k_chunkscan<<<147, 256, 0, stream>>>(cntP, rowptrP, bsumP, NPn);
  k_scanb<<<1, 256, 0, stream>>>(bsumL, 49);
  k_scanb<<<1, 256, 0, stream>>>(bsumP, 147);
  k_addoff<<<196, 256, 0, stream>>>(rowptrL, cursorL, bsumL, NLn);
  k_addoff<<<586, 256, 0, stream>>>(rowptrP, cursorP, bsumP, NPn);
  k_place<<<1954, 256, 0, stream>>>(esrc, edst, ea, lbatch, cursorL, cursorP,
                                    edgeL, rbfL, srcP, rbfP);

  unsigned short *xlc = xl0, *xln = xl1, *xpc = xp0, *xpn = xp1;
  for (int l = 0; l < 3; ++l){
    int ilp = 2*l, ipl = 2*l + 1;
    k_conv2<<<NBP + NBL, 256, 0, stream>>>(
        xpc, xlc, xpn, xln, xp_s, xl_s,
        rowptrP, srcP, rbfP, rowptrL, (const int*)edgeL + 1, rbfL,
        Wb + ilp*1024, bb + ilp*128, wcat + ilp*32768, bconv + ilp*128,
        Wb + ipl*1024, bb + ipl*128, wcat + ipl*32768, bconv + ipl*128);
    unsigned short* t;
    t = xlc; xlc = xln; xln = t;
    t = xpc; xpc = xpn; xpn = t;
  }

  // b1 folded into h_l here (bias arg); protein part gets no bias
  k_hproj_mfma<<<NBL, 256, 0, stream>>>(xl_s, w1t, b1, h_l, NLn);
  k_hproj_mfma<<<NBP, 256, 0, stream>>>(xp_s, w1t + 65536, nullptr, h_p, NPn);

  k_readout3<<<En/32, 256, 0, stream>>>(h_l, h_p, edgeL, vvec,
                                        w2t, b2, wmt, bm, out, mmax);
  k_final<<<128, 256, 0, stream>>>(mmax, out);
}